// Round 1
// 544.009 us; speedup vs baseline: 1.1527x; 1.1527x over previous
//
#include <hip/hip_runtime.h>

// ---------------------------------------------------------------------------
// WriteMemory: B=512, D_MODEL=2048, H=8, D_MEM=128, M=512
// out = [next_memories (512*512*128) | next_mass (512*512*128)] fp32
// ---------------------------------------------------------------------------

typedef _Float16 half8  __attribute__((ext_vector_type(8)));
typedef _Float16 half4v __attribute__((ext_vector_type(4)));
typedef float    f32x4  __attribute__((ext_vector_type(4)));

#define NB      512
#define DMODEL  2048
#define NH      8
#define DMEM    128
#define NM      512
#define NMTOT   33554432     // 512*512*128

__device__ __forceinline__ f32x4 ntload4(const float* p) {
    return __builtin_nontemporal_load((const f32x4*)p);
}
__device__ __forceinline__ void ntstore4(float* p, f32x4 v) {
    __builtin_nontemporal_store(v, (f32x4*)p);
}

// ---------------------------------------------------------------------------
// K0a: fp32 -> fp16 convert
// ---------------------------------------------------------------------------
__global__ void cvt_f32_f16(const float* __restrict__ in, _Float16* __restrict__ out, int n4) {
    int i = blockIdx.x * blockDim.x + threadIdx.x;
    if (i < n4) {
        float4 v = ((const float4*)in)[i];
        half4v o;
        o[0] = (_Float16)v.x; o[1] = (_Float16)v.y;
        o[2] = (_Float16)v.z; o[3] = (_Float16)v.w;
        ((half4v*)out)[i] = o;
    }
}

// ---------------------------------------------------------------------------
// K0b: W [K=2048][N] fp32 -> Wt [N][2048] fp16
// ---------------------------------------------------------------------------
__global__ void transp_cvt(const float* __restrict__ W, _Float16* __restrict__ Wt, int N) {
    __shared__ float tile[32][33];
    const int k0 = blockIdx.x * 32, n0 = blockIdx.y * 32;
    const int c = threadIdx.x & 31, r0 = threadIdx.x >> 5;
#pragma unroll
    for (int i = 0; i < 4; i++) {
        int r = r0 + i * 8;
        tile[r][c] = W[(size_t)(k0 + r) * N + n0 + c];
    }
    __syncthreads();
#pragma unroll
    for (int i = 0; i < 4; i++) {
        int r = r0 + i * 8;
        Wt[(size_t)(n0 + r) * 2048 + k0 + c] = (_Float16)tile[c][r];
    }
}

// ---------------------------------------------------------------------------
// K0c: aq = elu(addresses)+1; sigI = sigmoid(interp)
// ---------------------------------------------------------------------------
__global__ void prep_aq(const float* __restrict__ addresses, const float* __restrict__ ilog,
                        float* __restrict__ aqF, _Float16* __restrict__ aqH,
                        float* __restrict__ sigI) {
    int i = blockIdx.x * 256 + threadIdx.x;
    float a = addresses[i];
    float v = a > 0.f ? a + 1.f : __expf(a);
    aqF[i] = v;
    aqH[i] = (_Float16)v;
    sigI[i] = 1.0f / (1.0f + __expf(-ilog[i]));
}

// ---------------------------------------------------------------------------
// K1: fused GEMM C[512][3072] over K=2048, fp16 MFMA 16x16x32.
// Double-buffered LDS + register prefetch: one barrier per K-iter,
// global loads for k+1 in flight during compute of k.
// ---------------------------------------------------------------------------
__global__ __launch_bounds__(256) void gemm_kv(
        const _Float16* __restrict__ key16,
        const _Float16* __restrict__ val16,
        const _Float16* __restrict__ WkT,
        const _Float16* __restrict__ WvT,
        const float* __restrict__ b_key,
        const float* __restrict__ b_val,
        float* __restrict__ akF,
        _Float16* __restrict__ vH) {
    __shared__ _Float16 As[2][64][72];
    __shared__ _Float16 Bs[2][64][72];

    const int t = threadIdx.x;
    const int m0 = blockIdx.x * 64;
    const int n0 = blockIdx.y * 64;
    const bool isK = (n0 < 1024);
    const _Float16* aSrc = isK ? key16 : val16;
    const _Float16* bSrc = isK ? (WkT + (size_t)n0 * 2048)
                               : (WvT + (size_t)(n0 - 1024) * 2048);

    const int w = t >> 6, lane = t & 63;
    const int col = lane & 15, q = lane >> 4;
    const int wm = (w & 1) * 32, wn = (w >> 1) * 32;

    // staging map: slots s = t, t+256 -> row = s>>3, chunk = s&7 (16B)
    const int row0 = t >> 3, ch = t & 7;
    const int row1 = (t + 256) >> 3;

    f32x4 acc[2][2];
#pragma unroll
    for (int i = 0; i < 2; i++)
#pragma unroll
        for (int j = 0; j < 2; j++) acc[i][j] = (f32x4){0.f, 0.f, 0.f, 0.f};

    // prefetch k0 = 0
    uint4 ra0 = *(const uint4*)(aSrc + (size_t)(m0 + row0) * 2048 + ch * 8);
    uint4 ra1 = *(const uint4*)(aSrc + (size_t)(m0 + row1) * 2048 + ch * 8);
    uint4 rb0 = *(const uint4*)(bSrc + (size_t)row0 * 2048 + ch * 8);
    uint4 rb1 = *(const uint4*)(bSrc + (size_t)row1 * 2048 + ch * 8);

    int buf = 0;
    for (int k0 = 0; k0 < 2048; k0 += 64) {
        *(uint4*)&As[buf][row0][ch * 8] = ra0;
        *(uint4*)&As[buf][row1][ch * 8] = ra1;
        *(uint4*)&Bs[buf][row0][ch * 8] = rb0;
        *(uint4*)&Bs[buf][row1][ch * 8] = rb1;
        if (k0 + 64 < 2048) {
            const int kn = k0 + 64;
            ra0 = *(const uint4*)(aSrc + (size_t)(m0 + row0) * 2048 + kn + ch * 8);
            ra1 = *(const uint4*)(aSrc + (size_t)(m0 + row1) * 2048 + kn + ch * 8);
            rb0 = *(const uint4*)(bSrc + (size_t)row0 * 2048 + kn + ch * 8);
            rb1 = *(const uint4*)(bSrc + (size_t)row1 * 2048 + kn + ch * 8);
        }
        __syncthreads();
#pragma unroll
        for (int ks = 0; ks < 2; ks++) {
            half8 a0 = *(const half8*)&As[buf][wm + col][ks * 32 + q * 8];
            half8 a1 = *(const half8*)&As[buf][wm + 16 + col][ks * 32 + q * 8];
            half8 b0 = *(const half8*)&Bs[buf][wn + col][ks * 32 + q * 8];
            half8 b1 = *(const half8*)&Bs[buf][wn + 16 + col][ks * 32 + q * 8];
            acc[0][0] = __builtin_amdgcn_mfma_f32_16x16x32_f16(a0, b0, acc[0][0], 0, 0, 0);
            acc[0][1] = __builtin_amdgcn_mfma_f32_16x16x32_f16(a0, b1, acc[0][1], 0, 0, 0);
            acc[1][0] = __builtin_amdgcn_mfma_f32_16x16x32_f16(a1, b0, acc[1][0], 0, 0, 0);
            acc[1][1] = __builtin_amdgcn_mfma_f32_16x16x32_f16(a1, b1, acc[1][1], 0, 0, 0);
        }
        buf ^= 1;
    }
    // epilogue: C/D layout col=lane&15, row=(lane>>4)*4+reg
#pragma unroll
    for (int mt = 0; mt < 2; mt++) {
#pragma unroll
        for (int nt = 0; nt < 2; nt++) {
            int n = n0 + wn + nt * 16 + col;
#pragma unroll
            for (int r = 0; r < 4; r++) {
                int m = m0 + wm + mt * 16 + q * 4 + r;
                float x = acc[mt][nt][r];
                if (isK) {
                    x += b_key[n];
                    akF[(size_t)m * 1024 + n] = (x > 0.f) ? (x + 1.f) : __expf(x);
                } else {
                    int nn = n - 1024;
                    x += b_val[nn];
                    vH[(size_t)m * 2048 + nn] = (_Float16)x;
                }
            }
        }
    }
}

// ---------------------------------------------------------------------------
// K3: per-batch mega-fused kernel. 1024 threads = 16 waves, 1 block/CU.
//  A: matT[e][d] fp16 in LDS (rank-8 outer product) + nrm[d]
//  B: sDen[m] = 1/(aq[m].nrm + 1e-5)
//  C: 8 steps (it 0..1 x mt 0..3). Per step:
//     - issue next step's mem/wms/sigI loads (register double-buffer; raw
//       s_barrier + lgkmcnt(0) only, so prefetch survives barriers)
//     - MFMA: wave (wq,slice) computes 16 m-rows x 32 e (update+logit)
//     - block-level restage: acc -> uT/gT[64][132] in LDS
//     - coalesced IO: lane <-> consecutive 16B; each load/store instr covers
//       2 x 512B full rows (was 16 x 64B segments) for mem/wms/sigI/out.
// LDS: 69632 + 33792 + 33792 + 4096 + 4096 + 512 + 2048 = 147968 B -> 1 blk/CU
// ---------------------------------------------------------------------------
struct PFBuf { f32x4 pm[2]; f32x4 pw[2]; f32x4 ps[2]; };

__global__ __launch_bounds__(1024, 1) void fused_mem(
    const float* __restrict__ akF,        // [512][1024]
    const _Float16* __restrict__ vH,      // [512][2048]
    const _Float16* __restrict__ aqH,     // [512][128]
    const float* __restrict__ aqF,        // [512][128]
    const float* __restrict__ sigI,       // [512][128]
    const float* __restrict__ memories,   // [512][512][128]
    const float* __restrict__ write_mass, // [512][512][128]
    const unsigned char* __restrict__ bmask,
    float* __restrict__ out) {
    __shared__ _Float16 matT[256][DMEM + 8];   // 69632 B
    __shared__ float    uT[64][132];           // 33792 B (stride 132: <=2-way banks)
    __shared__ float    gT[64][132];           // 33792 B
    __shared__ float    sA[NH][DMEM];          // 4096 B
    __shared__ _Float16 sV[NH][256];           // 4096 B
    __shared__ float    sNrm[DMEM];            // 512 B
    __shared__ float    sDen[NM];              // 2048 B

    const int b = blockIdx.x;
    const int t = threadIdx.x;
    const int w = t >> 6, lane = t & 63;
    const int col = lane & 15, q = lane >> 4;
    const int wq = w >> 2, slice = w & 3;
    const int lr = lane >> 5, e4 = (lane & 31) * 4;   // IO lane map
    const size_t obase = (size_t)b * (NM * DMEM);

    PFBuf A, B;

    // step s: it = s>>2, mt = s&3. Wave (wq,slice) owns m-rows
    //   mrowBase(s) = (wq + (s>>2)*4)*64 + (s&3)*16 .. +15
    // IO: lane handles m = mrowBase + slice*4 + p*2 + lr, e = e4..e4+3.
    auto pf_issue = [&](PFBuf& pb, int s) {
        const int mrow = (wq + (s >> 2) * 4) * 64 + (s & 3) * 16 + slice * 4 + lr;
#pragma unroll
        for (int p = 0; p < 2; p++) {
            const size_t gi = (size_t)(mrow + p * 2) * 128 + e4;
            pb.pm[p] = ntload4(memories + obase + gi);
            pb.pw[p] = ntload4(write_mass + obase + gi);
            pb.ps[p] = *(const f32x4*)(sigI + gi);
        }
    };

    // issue step-0 loads immediately: they overlap the whole prologue
    pf_issue(A, 0);

    // ---- stage ak[b], v[b] ----
    if (t < 256) {
        ((float4*)&sA[0][0])[t] = ((const float4*)(akF + (size_t)b * 1024))[t];
        ((uint4*)&sV[0][0])[t]  = ((const uint4*)(vH + (size_t)b * 2048))[t];
    }
    __syncthreads();

    // ---- normalizer ----
    if (t < 128) {
        float s = 0.f;
#pragma unroll
        for (int h = 0; h < NH; h++) s += sA[h][t];
        sNrm[t] = s;
    }

    // ---- matT build: 1024 threads, each 4 d x 8 e ----
    {
        const int d0 = (t & 31) * 4;
        const int e0 = (t >> 5) * 8;
        float c[8][4];
#pragma unroll
        for (int e = 0; e < 8; e++)
#pragma unroll
            for (int d = 0; d < 4; d++) c[e][d] = 0.f;
#pragma unroll
        for (int h = 0; h < NH; h++) {
            float4 av = *(const float4*)&sA[h][d0];
            half8 vv = *(const half8*)&sV[h][e0];
#pragma unroll
            for (int e = 0; e < 8; e++) {
                float vf = (float)vv[e];
                c[e][0] += av.x * vf; c[e][1] += av.y * vf;
                c[e][2] += av.z * vf; c[e][3] += av.w * vf;
            }
        }
#pragma unroll
        for (int e = 0; e < 8; e++) {
            half4v o;
            o[0] = (_Float16)c[e][0]; o[1] = (_Float16)c[e][1];
            o[2] = (_Float16)c[e][2]; o[3] = (_Float16)c[e][3];
            *(half4v*)&matT[e0 + e][d0] = o;
        }
    }
    __syncthreads();

    // ---- denominators: 16 passes, 32 m per pass ----
    {
        const int l32 = lane & 31;
        const int hh = lane >> 5;
        const float4 nv = *(const float4*)&sNrm[l32 * 4];
#pragma unroll 4
        for (int pass = 0; pass < 16; pass++) {
            int m = pass * 32 + w * 2 + hh;
            float4 qv = *(const float4*)(aqF + (size_t)m * 128 + l32 * 4);
            float s = qv.x * nv.x + qv.y * nv.y + qv.z * nv.z + qv.w * nv.w;
            s += __shfl_xor(s, 1);  s += __shfl_xor(s, 2);  s += __shfl_xor(s, 4);
            s += __shfl_xor(s, 8);  s += __shfl_xor(s, 16);
            if (l32 == 0) sDen[m] = 1.0f / (s + 1e-5f);
        }
    }
    __syncthreads();

    // ---- phase C ----
    const float wfscale = (bmask[b] != 0) ? 0.0f : 0.7f;

    auto do_step = [&](int s, PFBuf& cur, PFBuf& nxt) {
        // 1. prefetch next step (stays in flight across the raw barriers)
        if (s < 7) pf_issue(nxt, s + 1);

        // 2. MFMA: acc[nt], nt 0/1 = update e-halves, 2/3 = logit e-halves
        const int mrowBase = (wq + (s >> 2) * 4) * 64 + (s & 3) * 16;
        f32x4 acc[4];
#pragma unroll
        for (int nt = 0; nt < 4; nt++) acc[nt] = (f32x4){0.f, 0.f, 0.f, 0.f};
#pragma unroll
        for (int ks = 0; ks < 4; ks++) {
            const half8 af = *(const half8*)(aqH + (size_t)(mrowBase + col) * 128
                                             + ks * 32 + q * 8);
#pragma unroll
            for (int nt = 0; nt < 4; nt++) {
                const half8 bf = *(const half8*)&matT[slice * 32 + (nt & 1) * 16
                                                      + (nt >> 1) * 128 + col]
                                                     [ks * 32 + q * 8];
                acc[nt] = __builtin_amdgcn_mfma_f32_16x16x32_f16(af, bf, acc[nt], 0, 0, 0);
            }
        }

        // 3. barrier 1: previous step's uT/gT readers are done (WAR).
        //    raw s_barrier + lgkmcnt(0): does NOT drain vmcnt -> prefetch lives.
        asm volatile("s_waitcnt lgkmcnt(0)" ::: "memory");
        __builtin_amdgcn_s_barrier();
        __builtin_amdgcn_sched_barrier(0);

        // 4. restage: D layout col=lane&15 (=e), row=q*4+r (=m-local)
        const int r0 = wq * 16 + q * 4;
#pragma unroll
        for (int r = 0; r < 4; r++) {
            uT[r0 + r][slice * 32 + col]      = acc[0][r];
            uT[r0 + r][slice * 32 + 16 + col] = acc[1][r];
            gT[r0 + r][slice * 32 + col]      = acc[2][r];
            gT[r0 + r][slice * 32 + 16 + col] = acc[3][r];
        }

        // 5. barrier 2: all writes visible
        asm volatile("s_waitcnt lgkmcnt(0)" ::: "memory");
        __builtin_amdgcn_s_barrier();
        __builtin_amdgcn_sched_barrier(0);

        // 6. coalesced IO: wave w owns tile rows w*4 .. w*4+3 (full 512B rows)
#pragma unroll
        for (int p = 0; p < 2; p++) {
            const int row = w * 4 + p * 2 + lr;
            const int m = mrowBase + slice * 4 + p * 2 + lr;
            const f32x4 u = *(const f32x4*)&uT[row][e4];
            const f32x4 g = *(const f32x4*)&gT[row][e4];
            const float rc = sDen[m];
            const size_t gi = obase + (size_t)m * 128 + e4;
            f32x4 o1, o2;
#pragma unroll
            for (int j = 0; j < 4; j++) {
                const float upd = u[j] * rc;
                const float wl  = g[j] * rc;
                const float wpb = 1.0f / (1.0f + __expf(-wl));
                const float wf  = wfscale * wpb * cur.ps[p][j];
                o1[j] = cur.pm[p][j] + wf * (upd - cur.pm[p][j]);
                o2[j] = cur.pw[p][j] + wf;
            }
            ntstore4(out + gi, o1);
            ntstore4(out + NMTOT + gi, o2);
        }
    };

    for (int s2 = 0; s2 < 8; s2 += 2) {
        do_step(s2,     A, B);
        do_step(s2 + 1, B, A);
    }
}

// ---------------------------------------------------------------------------
extern "C" void kernel_launch(void* const* d_in, const int* in_sizes, int n_in,
                              void* d_out, int out_size, void* d_ws, size_t ws_size,
                              hipStream_t stream) {
    const float* key        = (const float*)d_in[0];
    const float* values     = (const float*)d_in[1];
    const float* memories   = (const float*)d_in[2];
    const float* write_mass = (const float*)d_in[3];
    const unsigned char* bm = (const unsigned char*)d_in[4];
    const float* W_key      = (const float*)d_in[5];
    const float* b_key      = (const float*)d_in[6];
    const float* W_val      = (const float*)d_in[7];
    const float* b_val      = (const float*)d_in[8];
    const float* addresses  = (const float*)d_in[9];
    const float* ilog       = (const float*)d_in[10];
    float* out = (float*)d_out;

    char* ws = (char*)d_ws;
    _Float16* key16 = (_Float16*)ws;  ws += (size_t)512 * 2048 * 2;
    _Float16* val16 = (_Float16*)ws;  ws += (size_t)512 * 2048 * 2;
    _Float16* WkT   = (_Float16*)ws;  ws += (size_t)1024 * 2048 * 2;
    _Float16* WvT   = (_Float16*)ws;  ws += (size_t)2048 * 2048 * 2;
    float*    akF   = (float*)ws;     ws += (size_t)512 * 1024 * 4;
    _Float16* vH    = (_Float16*)ws;  ws += (size_t)512 * 2048 * 2;
    float*    aqF   = (float*)ws;     ws += (size_t)512 * 128 * 4;
    _Float16* aqH   = (_Float16*)ws;  ws += (size_t)512 * 128 * 2;
    float*    sigI  = (float*)ws;     ws += (size_t)512 * 128 * 4;

    cvt_f32_f16<<<1024, 256, 0, stream>>>(key, key16, 262144);
    cvt_f32_f16<<<1024, 256, 0, stream>>>(values, val16, 262144);
    transp_cvt<<<dim3(64, 32), 256, 0, stream>>>(W_key, WkT, 1024);
    transp_cvt<<<dim3(64, 64), 256, 0, stream>>>(W_val, WvT, 2048);
    prep_aq<<<256, 256, 0, stream>>>(addresses, ilog, aqF, aqH, sigI);
    gemm_kv<<<dim3(8, 48), 256, 0, stream>>>(key16, val16, WkT, WvT, b_key, b_val, akF, vH);
    fused_mem<<<512, 1024, 0, stream>>>(akF, vH, aqH, aqF, sigI, memories, write_mass, bm, out);
}